// Round 1
// baseline (132.587 us; speedup 1.0000x reference)
//
#include <hip/hip_runtime.h>
#include <hip/hip_bf16.h>

// Problem constants (fixed by the reference):
//   svPositionsAtT0: (B=64, N=63, 3)  f32
//   svEncoding:      (B=64, N=63, 512) f32
//   lengths:         (B=64,) i32
//   out:             (B, 512, 28, 28) f32, zero-init + scatter-max
#define NSV    63
#define HID    512
#define GW     28
#define GH     28
#define CELLS  (GW * GH)      // 784
#define HCHUNK 16             // h-values per block
#define NTHREADS 256

__global__ __launch_bounds__(NTHREADS)
void scatter_grid_kernel(const float* __restrict__ pos,
                         const float* __restrict__ enc,
                         const int*   __restrict__ lengths,
                         float*       __restrict__ out) {
    const int b      = blockIdx.y;
    const int h_base = blockIdx.x * HCHUNK;
    const int t      = threadIdx.x;

    __shared__ int   cell_s[NSV];
    __shared__ float enc_s[NSV * HCHUNK];          // [n][h]  4 KB
    __shared__ float grid_s[HCHUNK * CELLS];       // [h][c]  50 KB, contiguous == out layout

    // ---- 1. per-agent cell index (+validity) ----
    if (t < NSV) {
        const float x = pos[((size_t)b * NSV + t) * 3 + 0];
        const float y = pos[((size_t)b * NSV + t) * 3 + 1];
        const int len = lengths[b];
        // exact replication of jnp: (x * 28) / 224 in f32, trunc toward zero
        const int xi = (int)(x * 28.0f / 224.0f);
        const int yi = (int)(y * 28.0f / 224.0f);
        const bool valid = (t < len) && (xi < GW) && (yi < GH);
        const int xc = min(max(xi, 0), GW - 1);
        const int yc = min(max(yi, 0), GH - 1);
        cell_s[t] = valid ? (xc * GH + yc) : -1;
    }

    // ---- 2. stage encoding slice: enc[b, n, h_base:h_base+16] ----
    {
        const int n = t >> 2;        // 0..63
        const int q = t & 3;         // float4 index within the 16-h slice
        if (n < NSV) {
            const float4 v = ((const float4*)(enc + ((size_t)b * NSV + n) * HID + h_base))[q];
            ((float4*)(enc_s + n * HCHUNK))[q] = v;
        }
    }

    // ---- 3. zero the LDS grid tile ----
    {
        float4* g4 = (float4*)grid_s;
        const float4 z = make_float4(0.f, 0.f, 0.f, 0.f);
        #pragma unroll
        for (int i = t; i < HCHUNK * CELLS / 4; i += NTHREADS) g4[i] = z;
    }
    __syncthreads();

    // ---- 4. race-free scatter-max: thread (h, part) owns cells with c%16==part ----
    {
        const int h    = t >> 4;     // 0..15
        const int part = t & 15;
        float* row = grid_s + h * CELLS;
        #pragma unroll
        for (int n = 0; n < NSV; ++n) {
            const int c = cell_s[n];
            if (c >= 0 && (c & 15) == part) {
                const float v = enc_s[n * HCHUNK + h];
                if (v > row[c]) row[c] = v;   // row starts at 0 -> implicit max(0, .)
            }
        }
    }
    __syncthreads();

    // ---- 5. flat coalesced writeout: out[b][h_base..h_base+16][*] is contiguous ----
    {
        float* outb = out + ((size_t)b * HID + h_base) * CELLS;
        const float4* s4 = (const float4*)grid_s;
        float4* d4 = (float4*)outb;
        #pragma unroll
        for (int i = t; i < HCHUNK * CELLS / 4; i += NTHREADS) d4[i] = s4[i];
    }
}

extern "C" void kernel_launch(void* const* d_in, const int* in_sizes, int n_in,
                              void* d_out, int out_size, void* d_ws, size_t ws_size,
                              hipStream_t stream) {
    const float* pos     = (const float*)d_in[0];   // (B, 63, 3)
    const float* enc     = (const float*)d_in[1];   // (B, 63, 512)
    const int*   lengths = (const int*)d_in[2];     // (B,)
    float*       out     = (float*)d_out;           // (B, 512, 28, 28)

    const int B = in_sizes[2];                      // 64

    dim3 grid(HID / HCHUNK, B);                     // (32, 64)
    dim3 block(NTHREADS);
    scatter_grid_kernel<<<grid, block, 0, stream>>>(pos, enc, lengths, out);
}

// Round 2
// 118.654 us; speedup vs baseline: 1.1174x; 1.1174x over previous
//
#include <hip/hip_runtime.h>
#include <hip/hip_bf16.h>

// svPositionsAtT0: (B=64, N=63, 3)  f32
// svEncoding:      (B=64, N=63, 512) f32
// lengths:         (B=64,) i32
// out:             (B, 512, 28, 28) f32 = max(0, scatter-max of valid agent encodings)
#define NSV    63
#define HID    512
#define GW     28
#define GH     28
#define CELLS  (GW * GH)      // 784
#define HCHUNK 16             // h-values per block
#define NTHREADS 256
#define NF4    (HCHUNK * CELLS / 4)   // 3136 float4 per block tile
#define F4ROW  (CELLS / 4)            // 196 float4 per h-row

__global__ __launch_bounds__(NTHREADS)
void scatter_grid_kernel(const float* __restrict__ pos,
                         const float* __restrict__ enc,
                         const int*   __restrict__ lengths,
                         float*       __restrict__ out) {
    const int b      = blockIdx.y;
    const int h_base = blockIdx.x * HCHUNK;
    const int t      = threadIdx.x;

    __shared__ unsigned long long mask_s[CELLS];   // per-cell agent bitmask, 6.3 KB
    __shared__ float enc_s[NSV * HCHUNK];          // [n][h], 4 KB

    // ---- zero the masks ----
    for (int c = t; c < CELLS; c += NTHREADS) mask_s[c] = 0ull;

    // ---- stage encoding slice: enc[b, n, h_base:h_base+16] (64B per agent) ----
    {
        const int n = t >> 2;        // 0..63
        const int q = t & 3;         // float4 within the 16-h slice
        if (n < NSV) {
            const float4 v = ((const float4*)(enc + ((size_t)b * NSV + n) * HID + h_base))[q];
            ((float4*)(enc_s + n * HCHUNK))[q] = v;
        }
    }
    __syncthreads();   // mask zeroing must complete before atomicOr

    // ---- per-agent cell index + validity -> set bit in cell's mask ----
    if (t < NSV) {
        const float x = pos[((size_t)b * NSV + t) * 3 + 0];
        const float y = pos[((size_t)b * NSV + t) * 3 + 1];
        const int len = lengths[b];
        // exact replication of jnp: (x * 28) / 224 in f32, trunc toward zero
        const int xi = (int)(x * 28.0f / 224.0f);
        const int yi = (int)(y * 28.0f / 224.0f);
        if ((t < len) && (xi < GW) && (yi < GH)) {
            const int xc = min(max(xi, 0), GW - 1);
            const int yc = min(max(yi, 0), GH - 1);
            atomicOr(&mask_s[xc * GH + yc], 1ull << t);
        }
    }
    __syncthreads();

    // ---- streaming writeout: compute each float4 on the fly ----
    // out[b][h_base..h_base+16][0..784) is one contiguous 12544-float range.
    float4* d4 = (float4*)(out + ((size_t)b * HID + h_base) * CELLS);
    for (int i = t; i < NF4; i += NTHREADS) {
        const int h = i / F4ROW;          // 0..15
        const int c = (i - h * F4ROW) * 4;
        float4 v = make_float4(0.f, 0.f, 0.f, 0.f);
        #pragma unroll
        for (int j = 0; j < 4; ++j) {
            unsigned long long m = mask_s[c + j];
            float val = 0.f;              // grid init 0 -> implicit max with 0
            while (m) {
                const int n = __ffsll(m) - 1;
                m &= m - 1;
                val = fmaxf(val, enc_s[n * HCHUNK + h]);
            }
            (&v.x)[j] = val;
        }
        d4[i] = v;
    }
}

extern "C" void kernel_launch(void* const* d_in, const int* in_sizes, int n_in,
                              void* d_out, int out_size, void* d_ws, size_t ws_size,
                              hipStream_t stream) {
    const float* pos     = (const float*)d_in[0];   // (B, 63, 3)
    const float* enc     = (const float*)d_in[1];   // (B, 63, 512)
    const int*   lengths = (const int*)d_in[2];     // (B,)
    float*       out     = (float*)d_out;           // (B, 512, 28, 28)

    const int B = in_sizes[2];                      // 64

    dim3 grid(HID / HCHUNK, B);                     // (32, 64) = 2048 blocks
    dim3 block(NTHREADS);
    scatter_grid_kernel<<<grid, block, 0, stream>>>(pos, enc, lengths, out);
}